// Round 1
// baseline (913.182 us; speedup 1.0000x reference)
//
#include <hip/hip_runtime.h>

#define BS_N 1048576
#define NH 64
#define NK 64

// ws layout (floats): [0:512) colsum replicas (8 x 64), [512:576) c2[k]
#define WS_C2_OFF 512

__device__ __forceinline__ float frcp(float x) { return __builtin_amdgcn_rcpf(x); }

// K0: zero colsum replicas, precompute ||c_k||^2. One block, 128 threads.
__global__ void k0_init(const float* __restrict__ c, float* __restrict__ ws) {
    const int t = threadIdx.x;
    for (int i = t; i < 512; i += 128) ws[i] = 0.f;
    if (t < 64) {
        const float* row = c + t * NH;
        float s0 = 0.f, s1 = 0.f, s2 = 0.f, s3 = 0.f;
#pragma unroll
        for (int h = 0; h < NH; h += 4) {
            s0 = fmaf(row[h + 0], row[h + 0], s0);
            s1 = fmaf(row[h + 1], row[h + 1], s1);
            s2 = fmaf(row[h + 2], row[h + 2], s2);
            s3 = fmaf(row[h + 3], row[h + 3], s3);
        }
        ws[WS_C2_OFF + t] = (s0 + s1) + (s2 + s3);
    }
}

// K1: per row -> normalized Q row; block-level column sums -> replicated global atomics.
__global__ __launch_bounds__(128) void k1_q(const float* __restrict__ z,
                                            const float* __restrict__ c,
                                            float* __restrict__ ws,
                                            float* __restrict__ Q) {
    __shared__ float qs[128 * 65];  // stride 65: conflict-free rows AND columns
    __shared__ float rs[128];
    __shared__ float cpart[2][64];
    const int t = threadIdx.x;
    const long long row = (long long)blockIdx.x * 128 + t;
    const float* __restrict__ c2p = ws + WS_C2_OFF;
    float* colsum = ws + (size_t)(blockIdx.x & 7) * 64;

    // z row -> registers (16B/lane streaming loads)
    const float4* z4 = reinterpret_cast<const float4*>(z) + row * 16;
    float zr[NH];
#pragma unroll
    for (int i = 0; i < 16; i++) {
        float4 v = z4[i];
        zr[4 * i + 0] = v.x; zr[4 * i + 1] = v.y;
        zr[4 * i + 2] = v.z; zr[4 * i + 3] = v.w;
    }
    float z20 = 0.f, z21 = 0.f, z22 = 0.f, z23 = 0.f;
#pragma unroll
    for (int h = 0; h < NH; h += 4) {
        z20 = fmaf(zr[h + 0], zr[h + 0], z20);
        z21 = fmaf(zr[h + 1], zr[h + 1], z21);
        z22 = fmaf(zr[h + 2], zr[h + 2], z22);
        z23 = fmaf(zr[h + 3], zr[h + 3], z23);
    }
    const float z2 = (z20 + z21) + (z22 + z23);

    float rowsum = 0.f;
    for (int k = 0; k < NK; k++) {
        // wave-uniform centroid row -> scalar loads / broadcast
        const float4* c4 = reinterpret_cast<const float4*>(c) + k * 16;
        float a0 = 0.f, a1 = 0.f, a2 = 0.f, a3 = 0.f;
#pragma unroll
        for (int i = 0; i < 16; i++) {
            float4 cv = c4[i];
            a0 = fmaf(zr[4 * i + 0], cv.x, a0);
            a1 = fmaf(zr[4 * i + 1], cv.y, a1);
            a2 = fmaf(zr[4 * i + 2], cv.z, a2);
            a3 = fmaf(zr[4 * i + 3], cv.w, a3);
        }
        const float dot = (a0 + a1) + (a2 + a3);
        float d2 = z2 + c2p[k] - 2.f * dot;
        d2 = fmaxf(d2, 0.f);
        const float sim = sqrtf(d2);
        const float qu = frcp(1.f + sim);  // (1+sim/a)^(-(a+1)/2), a=1
        rowsum += qu;
        qs[t * 65 + k] = qu;
    }
    const float rinv = frcp(rowsum);
    rs[t] = rinv;
    __syncthreads();

    // normalized Q row -> global (float4)
    float4* Q4 = reinterpret_cast<float4*>(Q) + row * 16;
#pragma unroll
    for (int i = 0; i < 16; i++) {
        float4 v;
        v.x = qs[t * 65 + 4 * i + 0] * rinv;
        v.y = qs[t * 65 + 4 * i + 1] * rinv;
        v.z = qs[t * 65 + 4 * i + 2] * rinv;
        v.w = qs[t * 65 + 4 * i + 3] * rinv;
        Q4[i] = v;
    }

    // block column sums of normalized Q (conflict-free column reads: addr = rr*65+k)
    const int k = t & 63, g = t >> 6;
    float s = 0.f;
#pragma unroll 8
    for (int r = 0; r < 64; r++) {
        const int rr = g * 64 + r;
        s = fmaf(qs[rr * 65 + k], rs[rr], s);
    }
    cpart[g][k] = s;
    __syncthreads();
    if (t < 64) atomicAdd(&colsum[t], cpart[0][t] + cpart[1][t]);
}

// K2: P = rownorm(Q^2 / colsum). Reversed block order for L3 reuse of Q's tail.
__global__ __launch_bounds__(256) void k2_p(const float* __restrict__ ws,
                                            const float* __restrict__ Q,
                                            float* __restrict__ P) {
    __shared__ __align__(16) float rcs[64];
    const int t = threadIdx.x;
    if (t < 64) {
        float s = 0.f;
#pragma unroll
        for (int rep = 0; rep < 8; rep++) s += ws[rep * 64 + t];
        rcs[t] = frcp(s);
    }
    __syncthreads();

    const long long row = (long long)(gridDim.x - 1 - blockIdx.x) * 256 + t;
    const float4* Q4 = reinterpret_cast<const float4*>(Q) + row * 16;
    float4* P4 = reinterpret_cast<float4*>(P) + row * 16;

    float pu[NK];
    float s0 = 0.f, s1 = 0.f, s2 = 0.f, s3 = 0.f;
#pragma unroll
    for (int i = 0; i < 16; i++) {
        float4 v = Q4[i];
        float4 cc = *reinterpret_cast<const float4*>(&rcs[4 * i]);
        pu[4 * i + 0] = v.x * v.x * cc.x; s0 += pu[4 * i + 0];
        pu[4 * i + 1] = v.y * v.y * cc.y; s1 += pu[4 * i + 1];
        pu[4 * i + 2] = v.z * v.z * cc.z; s2 += pu[4 * i + 2];
        pu[4 * i + 3] = v.w * v.w * cc.w; s3 += pu[4 * i + 3];
    }
    const float rinv = frcp((s0 + s1) + (s2 + s3));
#pragma unroll
    for (int i = 0; i < 16; i++) {
        float4 o;
        o.x = pu[4 * i + 0] * rinv;
        o.y = pu[4 * i + 1] * rinv;
        o.z = pu[4 * i + 2] * rinv;
        o.w = pu[4 * i + 3] * rinv;
        P4[i] = o;
    }
}

extern "C" void kernel_launch(void* const* d_in, const int* in_sizes, int n_in,
                              void* d_out, int out_size, void* d_ws, size_t ws_size,
                              hipStream_t stream) {
    const float* z = (const float*)d_in[0];
    const float* c = (const float*)d_in[1];
    float* Q = (float*)d_out;
    float* P = (float*)d_out + (size_t)BS_N * NK;
    float* ws = (float*)d_ws;

    k0_init<<<1, 128, 0, stream>>>(c, ws);
    k1_q<<<BS_N / 128, 128, 0, stream>>>(z, c, ws, Q);
    k2_p<<<BS_N / 256, 256, 0, stream>>>(ws, Q, P);
}